// Round 3
// baseline (627.392 us; speedup 1.0000x reference)
//
#include <hip/hip_runtime.h>

// GCN 2-layer, gather-based (atomic-free aggregation).
// N=100000, F_in=512, H=16, C=40, E=3200000.
//
// Algebra: A_hat h = D^-1/2 (A+I) D^-1/2 h. With hs = dinv*h (pre-scaled),
// (A_hat h)[i] = dinv[i] * ( sum_{s in N(i)} hs[s] + hs[i] ).
// Layer2 uses aggregate-then-transform: A_hat(h2 W2) == (A_hat h2) W2.
// Edges are counting-sorted by dst once per call (CSR); both layers gather.

#define TPB 256

// ---------------------------------------------------------------- zero counts
__global__ void k_init(int* __restrict__ cnt, int n) {
    int i = blockIdx.x * TPB + threadIdx.x;
    if (i < n) cnt[i] = 0;
}

// ---------------------------------------------------------------- degree histogram (int)
__global__ void k_count(const int* __restrict__ dst, int* __restrict__ cnt, int E) {
    int e = blockIdx.x * TPB + threadIdx.x;
    if (e < E) atomicAdd(&cnt[dst[e]], 1);
}

__global__ void k_dinv(const int* __restrict__ cnt, float* __restrict__ dinv, int n) {
    int i = blockIdx.x * TPB + threadIdx.x;
    if (i < n) dinv[i] = rsqrtf((float)(cnt[i] + 1));   // +1 self loop
}

// ---------------------------------------------------------------- exclusive scan (3 kernels)
__global__ void k_scan1(const int* __restrict__ cnt, int* __restrict__ rs,
                        int* __restrict__ partials, int n) {
    __shared__ int s[TPB];
    int tid = threadIdx.x;
    int i = blockIdx.x * TPB + tid;
    int c = (i < n) ? cnt[i] : 0;
    s[tid] = c;
    __syncthreads();
#pragma unroll
    for (int off = 1; off < TPB; off <<= 1) {
        int t = (tid >= off) ? s[tid - off] : 0;
        __syncthreads();
        s[tid] += t;
        __syncthreads();
    }
    if (i < n) rs[i] = s[tid] - c;           // exclusive within block
    if (tid == TPB - 1) partials[blockIdx.x] = s[tid];
}

__global__ void k_scan2(int* __restrict__ partials, int nb) {
    __shared__ int s[512];
    int tid = threadIdx.x;
    int p = (tid < nb) ? partials[tid] : 0;
    s[tid] = p;
    __syncthreads();
#pragma unroll
    for (int off = 1; off < 512; off <<= 1) {
        int t = (tid >= off) ? s[tid - off] : 0;
        __syncthreads();
        s[tid] += t;
        __syncthreads();
    }
    if (tid < nb) partials[tid] = s[tid] - p; // exclusive block offsets
}

__global__ void k_scan3(int* __restrict__ rs, int* __restrict__ cursor,
                        const int* __restrict__ partials, int n, int E) {
    int i = blockIdx.x * TPB + threadIdx.x;
    if (i < n) {
        int v = rs[i] + partials[blockIdx.x];
        rs[i] = v;
        cursor[i] = v;
    }
    if (i == 0) rs[n] = E;
}

// ---------------------------------------------------------------- fill CSR (sorted_src by dst bucket)
__global__ void k_fill(const int* __restrict__ src, const int* __restrict__ dst,
                       int* __restrict__ cursor, int* __restrict__ ssrc, int E) {
    int e = blockIdx.x * TPB + threadIdx.x;
    if (e >= E) return;
    int slot = atomicAdd(&cursor[dst[e]], 1);
    ssrc[slot] = src[e];
}

// ---------------------------------------------------------------- GEMM1: hs1[n,16] = dinv * (x[n,512] @ W1)
#define G1_ROWS 256
#define G1_KC 32
__global__ __launch_bounds__(TPB) void k_gemm1(const float* __restrict__ x,
                                               const float* __restrict__ W,
                                               const float* __restrict__ dinv,
                                               float* __restrict__ hs, int n) {
    __shared__ float xs[G1_ROWS][36];
    __shared__ float wl[G1_KC][16];
    const int tid = threadIdx.x;
    const int row0 = blockIdx.x * G1_ROWS;
    const int rg = tid >> 2;            // 0..63
    const int c0 = (tid & 3) * 4;       // 0,4,8,12

    float acc[4][4];
#pragma unroll
    for (int j = 0; j < 4; ++j)
#pragma unroll
        for (int c = 0; c < 4; ++c) acc[j][c] = 0.0f;

    for (int kc = 0; kc < 512; kc += G1_KC) {
        __syncthreads();
#pragma unroll
        for (int t = 0; t < 8; ++t) {
            int f4 = tid + TPB * t;
            int row = f4 >> 3;
            int kk = (f4 & 7) * 4;
            int grow = row0 + row;
            if (grow >= n) grow = n - 1;
            float4 v = *reinterpret_cast<const float4*>(&x[(size_t)grow * 512 + kc + kk]);
            *reinterpret_cast<float4*>(&xs[row][kk]) = v;
        }
        if (tid < 128) {
            int k = tid >> 2, cc = (tid & 3) * 4;
            *reinterpret_cast<float4*>(&wl[k][cc]) =
                *reinterpret_cast<const float4*>(&W[(size_t)(kc + k) * 16 + cc]);
        }
        __syncthreads();

#pragma unroll
        for (int k4 = 0; k4 < G1_KC; k4 += 4) {
            float w[4][4];
#pragma unroll
            for (int kk = 0; kk < 4; ++kk) {
                float4 wv = *reinterpret_cast<const float4*>(&wl[k4 + kk][c0]);
                w[kk][0] = wv.x; w[kk][1] = wv.y; w[kk][2] = wv.z; w[kk][3] = wv.w;
            }
#pragma unroll
            for (int j = 0; j < 4; ++j) {
                float4 xv = *reinterpret_cast<const float4*>(&xs[rg + 64 * j][k4]);
                float xk[4] = {xv.x, xv.y, xv.z, xv.w};
#pragma unroll
                for (int kk = 0; kk < 4; ++kk)
#pragma unroll
                    for (int c = 0; c < 4; ++c) acc[j][c] += xk[kk] * w[kk][c];
            }
        }
    }

#pragma unroll
    for (int j = 0; j < 4; ++j) {
        int grow = row0 + rg + 64 * j;
        if (grow < n) {
            float di = dinv[grow];
            float4 v = make_float4(acc[j][0] * di, acc[j][1] * di,
                                   acc[j][2] * di, acc[j][3] * di);
            *reinterpret_cast<float4*>(&hs[(size_t)grow * 16 + c0]) = v;
        }
    }
}

// ---------------------------------------------------------------- gather-agg layer1:
// hs2[i] = dinv[i] * relu( dinv[i]*(sum_{s} hs1[s] + hs1[i]) + b1 )
// One wave per node; lane = (j4, f): 4 edges in flight, 16 feats each.
__global__ __launch_bounds__(TPB) void k_aggA(const int* __restrict__ rs,
                                              const int* __restrict__ ssrc,
                                              const float* __restrict__ hs1,
                                              const float* __restrict__ dinv,
                                              const float* __restrict__ b1,
                                              float* __restrict__ hs2, int n) {
    int node = blockIdx.x * 4 + (threadIdx.x >> 6);
    if (node >= n) return;
    int lane = threadIdx.x & 63;
    int j4 = lane >> 4, f = lane & 15;
    int r0 = rs[node], r1 = rs[node + 1];
    float acc = 0.0f;
    for (int j = r0 + j4; j < r1; j += 4) {
        int s = ssrc[j];
        acc += hs1[(size_t)s * 16 + f];
    }
    acc += __shfl_xor(acc, 16);
    acc += __shfl_xor(acc, 32);
    if (j4 == 0) {
        float di = dinv[node];
        float self = hs1[(size_t)node * 16 + f];
        float v = fmaxf(di * (acc + self) + b1[f], 0.0f);
        hs2[(size_t)node * 16 + f] = di * v;
    }
}

// ---------------------------------------------------------------- gather-agg layer2:
// pre2[i] = dinv[i] * (sum_{s} hs2[s] + hs2[i])
__global__ __launch_bounds__(TPB) void k_aggB(const int* __restrict__ rs,
                                              const int* __restrict__ ssrc,
                                              const float* __restrict__ hs2,
                                              const float* __restrict__ dinv,
                                              float* __restrict__ pre2, int n) {
    int node = blockIdx.x * 4 + (threadIdx.x >> 6);
    if (node >= n) return;
    int lane = threadIdx.x & 63;
    int j4 = lane >> 4, f = lane & 15;
    int r0 = rs[node], r1 = rs[node + 1];
    float acc = 0.0f;
    for (int j = r0 + j4; j < r1; j += 4) {
        int s = ssrc[j];
        acc += hs2[(size_t)s * 16 + f];
    }
    acc += __shfl_xor(acc, 16);
    acc += __shfl_xor(acc, 32);
    if (j4 == 0) {
        float di = dinv[node];
        float self = hs2[(size_t)node * 16 + f];
        pre2[(size_t)node * 16 + f] = di * (acc + self);
    }
}

// ---------------------------------------------------------------- GEMM2: out[n,40] = pre2[n,16] @ W2 + b2
__global__ void k_gemm2f(const float* __restrict__ pre2, const float* __restrict__ W2,
                         const float* __restrict__ b2, float* __restrict__ out, int n) {
    __shared__ float wl[16 * 40];
    __shared__ float bl[40];
    int tid = threadIdx.x;
    for (int i = tid; i < 640; i += TPB) wl[i] = W2[i];
    if (tid < 40) bl[tid] = b2[tid];
    __syncthreads();
    int gid = blockIdx.x * TPB + tid;
    if (gid >= n * 40) return;
    int r = gid / 40, c = gid - r * 40;
    const float* pr = &pre2[(size_t)r * 16];
    float a = bl[c];
#pragma unroll
    for (int k = 0; k < 16; ++k) a += pr[k] * wl[k * 40 + c];
    out[gid] = a;
}

extern "C" void kernel_launch(void* const* d_in, const int* in_sizes, int n_in,
                              void* d_out, int out_size, void* d_ws, size_t ws_size,
                              hipStream_t stream) {
    const float* x  = (const float*)d_in[0];
    const int*   ei = (const int*)d_in[1];
    const float* W1 = (const float*)d_in[2];
    const float* b1 = (const float*)d_in[3];
    const float* W2 = (const float*)d_in[4];
    const float* b2 = (const float*)d_in[5];
    float* out = (float*)d_out;

    const int n = in_sizes[0] / 512;
    const int E = in_sizes[1] / 2;
    const int* src = ei;
    const int* dst = ei + E;
    const int NB = (n + TPB - 1) / TPB;          // scan blocks (391)

    // workspace layout
    char* w = (char*)d_ws;
    int*   cnt      = (int*)w;                 w += (size_t)n * 4;
    int*   rs       = (int*)w;                 w += (size_t)(n + 1) * 4;
    int*   cursor   = (int*)w;                 w += (size_t)n * 4;
    int*   partials = (int*)w;                 w += (size_t)(NB + 1) * 4;
    int*   ssrc     = (int*)w;                 w += (size_t)E * 4;
    float* dinv     = (float*)w;               w += (size_t)n * 4;
    float* hs1      = (float*)w;               w += (size_t)n * 16 * 4;
    float* hs2      = (float*)w;               w += (size_t)n * 16 * 4;
    float* pre2     = (float*)w;               // n*16*4

    k_init <<<NB, TPB, 0, stream>>>(cnt, n);
    k_count<<<(E + TPB - 1) / TPB, TPB, 0, stream>>>(dst, cnt, E);
    k_dinv <<<NB, TPB, 0, stream>>>(cnt, dinv, n);
    k_scan1<<<NB, TPB, 0, stream>>>(cnt, rs, partials, n);
    k_scan2<<<1, 512, 0, stream>>>(partials, NB);
    k_scan3<<<NB, TPB, 0, stream>>>(rs, cursor, partials, n, E);
    k_fill <<<(E + TPB - 1) / TPB, TPB, 0, stream>>>(src, dst, cursor, ssrc, E);
    k_gemm1<<<(n + G1_ROWS - 1) / G1_ROWS, TPB, 0, stream>>>(x, W1, dinv, hs1, n);
    k_aggA <<<(n + 3) / 4, TPB, 0, stream>>>(rs, ssrc, hs1, dinv, b1, hs2, n);
    k_aggB <<<(n + 3) / 4, TPB, 0, stream>>>(rs, ssrc, hs2, dinv, pre2, n);
    k_gemm2f<<<(n * 40 + TPB - 1) / TPB, TPB, 0, stream>>>(pre2, W2, b2, out, n);
}